// Round 2
// baseline (11038.277 us; speedup 1.0000x reference)
//
#include <hip/hip_runtime.h>
#include <hip/hip_bf16.h>
#include <type_traits>

// Problem constants
#define B_   32
#define S_   2048
#define I_   256
#define H_   256
#define NWG  16      // workgroups in the persistent kernel
#define NT   256     // threads per WG
#define UPW  16      // hidden units owned per WG (x4 gates = 64 columns)
#define TC   16      // timesteps per precompute WG
#define NG   4       // batch groups (pipeline depth)
#define MB   8       // batches per group

typedef __attribute__((ext_vector_type(8))) short short8;   // 8 x bf16 MFMA frag
typedef __attribute__((ext_vector_type(4))) float f32x4;
typedef unsigned long long u64;

__device__ __forceinline__ unsigned short f2bf(float f) {
  unsigned u = __builtin_bit_cast(unsigned, f);
  return (unsigned short)((u + 0x7FFFu + ((u >> 16) & 1u)) >> 16);  // RNE
}
__device__ __forceinline__ float bf2f(unsigned short b) {
  unsigned u = ((unsigned)b) << 16;
  return __builtin_bit_cast(float, u);
}
__device__ __forceinline__ float fast_rcp(float x) { return __builtin_amdgcn_rcpf(x); }
// |inputs| are bounded (<~8) in this net: no overflow concerns.
__device__ __forceinline__ float fast_tanh(float x) {
  return 1.f - 2.f * fast_rcp(__expf(2.f * x) + 1.f);
}
__device__ __forceinline__ float fast_sig(float x) {
  return fast_rcp(1.f + __expf(-x));
}
// Pack 2 hidden units into one exchange word: low dword = (hi0|hi1<<16),
// high dword = (lo0|lo1<<16) with tag in lo0's LSB.
__device__ __forceinline__ u64 packw(float v0, float v1, unsigned tagw) {
  unsigned short h0h = f2bf(v0);
  unsigned short h0l = f2bf(v0 - bf2f(h0h));
  unsigned short h1h = f2bf(v1);
  unsigned short h1l = f2bf(v1 - bf2f(h1h));
  unsigned hiw = (unsigned)h0h | ((unsigned)h1h << 16);
  unsigned low = (((unsigned)h0l & 0xFFFEu) | tagw) | ((unsigned)h1l << 16);
  return (u64)hiw | ((u64)low << 32);
}

// Barrier that does NOT drain vmcnt: LDS-producer/consumer ordering only.
// __syncthreads() would emit s_waitcnt vmcnt(0) and serialize the poll /
// zx prefetch pipeline (the round-1 stall).
__device__ __forceinline__ void bar_lds() {
  asm volatile("s_waitcnt lgkmcnt(0)" ::: "memory");
  __builtin_amdgcn_s_barrier();
  __builtin_amdgcn_sched_barrier(0);
}

// ===================== 4-group pipelined path =====================
// Exchange layout (u64 words): word = parity*4096 + g*1024 + b*128 + wg*8 + pair
// (parity = t&1, g = batch-group 0..3, b = batch-in-group 0..7, pair = unit
//  pair 0..7 within the WG's 16 units). Validity: tag bit == (t>>1)&1.

__global__ void pack_h0_4grp(const float* __restrict__ h0, u64* __restrict__ hex) {
  int idx = blockIdx.x * 256 + threadIdx.x;   // 0..4095 (parity-0 words)
  int g   = idx >> 10;
  int rem = idx & 1023;
  int b   = rem >> 7;
  int u2  = rem & 127;
  const float* hp = h0 + ((g * MB + b) * 256 + u2 * 2);
  hex[g * 1024 + rem] = packw(hp[0], hp[1], 0u);   // tag(t=0) = 0
}

// Full-chip precompute of zx = x@Wx + bias, stored compactly for M=8 phases:
// element(t, g, ug, gate=wv, q'<2, mm, r) at
//   ((t*4+g)*16+ug)*512 + wv*128 + (q'*16+mm)*4 + r       (256 MiB total)
__global__ __launch_bounds__(NT) void zx_precompute4(
    const float* __restrict__ x, const float* __restrict__ W,
    const float* __restrict__ bias, float* __restrict__ zx) {
  __shared__ unsigned short xlds[32 * 264];

  const int tid  = threadIdx.x;
  const int ug   = blockIdx.x & 15;
  const int tc   = blockIdx.x >> 4;
  const int lane = tid & 63;
  const int wv   = tid >> 6;     // wave = gate
  const int q    = lane >> 4;
  const int mm   = lane & 15;

  short8 wx[8];
  const int col = wv * 256 + ug * UPW + mm;
  const float bia = bias[col];
  #pragma unroll
  for (int kc = 0; kc < 8; ++kc) {
    short8 v;
    #pragma unroll
    for (int j = 0; j < 8; ++j)
      v[j] = (short)f2bf(W[(long)(kc * 32 + q * 8 + j) * 1024 + col]);
    wx[kc] = v;
  }

  for (int tt = 0; tt < TC; ++tt) {
    const int t = tc * TC + tt;
    const int xb = tid >> 3, xi0 = (tid & 7) * 32;
    const float* xp = x + ((long)xb * S_ + t) * I_ + xi0;
    #pragma unroll
    for (int k2 = 0; k2 < 4; ++k2) {
      f32x4 a  = *(const f32x4*)(xp + k2 * 8);
      f32x4 b2 = *(const f32x4*)(xp + k2 * 8 + 4);
      unsigned short u8[8];
      #pragma unroll
      for (int j = 0; j < 4; ++j) { u8[j] = f2bf(a[j]); u8[4 + j] = f2bf(b2[j]); }
      *(uint4*)&xlds[xb * 264 + xi0 + k2 * 8] = *(const uint4*)u8;
    }
    __syncthreads();
    f32x4 acc0 = {0.f, 0.f, 0.f, 0.f}, acc1 = {0.f, 0.f, 0.f, 0.f};
    #pragma unroll
    for (int kc = 0; kc < 8; ++kc) {
      short8 a0 = *(const short8*)&xlds[(mm)      * 264 + kc * 32 + q * 8];
      short8 a1 = *(const short8*)&xlds[(16 + mm) * 264 + kc * 32 + q * 8];
      acc0 = __builtin_amdgcn_mfma_f32_16x16x32_bf16(a0, wx[kc], acc0, 0, 0, 0);
      acc1 = __builtin_amdgcn_mfma_f32_16x16x32_bf16(a1, wx[kc], acc1, 0, 0, 0);
    }
    f32x4 s0, s1;
    #pragma unroll
    for (int r = 0; r < 4; ++r) { s0[r] = acc0[r] + bia; s1[r] = acc1[r] + bia; }
    // acc0: batches q*4+r (0..15) -> group q>>1, row-in-group (q&1)*4+r
    // acc1: batches 16..31        -> group 2+(q>>1)
    const long sub = wv * 128 + ((q & 1) * 16 + mm) * 4;
    *(f32x4*)(zx + (((long)t * NG + (q >> 1))     * 16 + ug) * 512 + sub) = s0;
    *(f32x4*)(zx + (((long)t * NG + 2 + (q >> 1)) * 16 + ug) * 512 + sub) = s1;
    __syncthreads();   // protect xlds before next stage
  }
}

// Persistent 4-group pipelined LSTM. Per step: 4 phases (one per batch group).
// Group g's h(t+1) is published at end of phase g(t), pre-blasted into
// registers at phase (g+2)&3 (2 phases after publish -> visible), and
// tag-checked at phase g(t+1) (load long returned). No vmcnt drains in loop.
__global__ __launch_bounds__(NT, 1) void lstm_persist4(
    const float* __restrict__ h0, const float* __restrict__ c0,
    float* __restrict__ out, u64* __restrict__ hex,
    const float* __restrict__ W, const float* __restrict__ zx) {

  __shared__ unsigned short hhp[NG][MB * 264];   // hi plane per group
  __shared__ unsigned short hlp[NG][MB * 264];   // lo plane per group
  __shared__ float zbuf[MB * 68];
  __shared__ u64 ownw[NG][64];                   // this WG's own words

  const int tid  = threadIdx.x;
  const int wg   = blockIdx.x;
  const int lane = tid & 63;
  const int wv   = tid >> 6;          // wave = gate (0..3)
  const int q    = lane >> 4;
  const int mm   = lane & 15;
  // this thread's polled unit-pair column is fixed (u2 = tid&127); if it falls
  // in our own WG's slice we never poll globally for it.
  const bool own = (((tid & 127) >> 3) == wg);

  // ---- one-time: Wh fragments (hi/lo bf16) for this wave's gate
  short8 whh[8], whl[8];
  const int col = wv * 256 + wg * UPW + mm;
  #pragma unroll
  for (int kc = 0; kc < 8; ++kc) {
    short8 vhh, vhl;
    #pragma unroll
    for (int j = 0; j < 8; ++j) {
      int k = kc * 32 + q * 8 + j;
      float whv = W[(long)(256 + k) * 1024 + col];
      unsigned short hhb = f2bf(whv);
      vhh[j] = (short)hhb;
      vhl[j] = (short)f2bf(whv - bf2f(hhb));
    }
    whh[kc] = vhh; whl[kc] = vhl;
  }

  // combine ownership (tid<128): batch-in-group cb, single unit cu
  const int cb = tid >> 4;       // 0..7
  const int cu = tid & 15;       // 0..15
  float cs4[NG];
  if (tid < 128) {
    #pragma unroll
    for (int g = 0; g < NG; ++g)
      cs4[g] = c0[(g * MB + cb) * 256 + wg * UPW + cu];
    if ((cu & 1) == 0) {
      #pragma unroll
      for (int g = 0; g < NG; ++g) {
        float v0 = h0[(g * MB + cb) * 256 + wg * UPW + cu];
        float v1 = h0[(g * MB + cb) * 256 + wg * UPW + cu + 1];
        ownw[g][cb * 8 + (cu >> 1)] = packw(v0, v1, 0u);
      }
    }
  }

  // pipeline registers: one pre-blast set per group
  u64 hv0[4], hv1[4], hv2[4], hv3[4];
  if (!own) {
    #pragma unroll
    for (int k = 0; k < 4; ++k) {
      hv0[k] = __hip_atomic_load(hex + 0 * 1024 + (k << 8) + tid,
                                 __ATOMIC_RELAXED, __HIP_MEMORY_SCOPE_AGENT);
      hv1[k] = __hip_atomic_load(hex + 1 * 1024 + (k << 8) + tid,
                                 __ATOMIC_RELAXED, __HIP_MEMORY_SCOPE_AGENT);
    }
  }

  f32x4 zr0, zr1, zr2, zr3;
  if (q < 2) {
    const long sub = wv * 128 + (lane & 31) * 4;
    zr0 = *(const f32x4*)(zx + ((long)(0 * NG + 0) * 16 + wg) * 512 + sub);
    zr1 = *(const f32x4*)(zx + ((long)(0 * NG + 1) * 16 + wg) * 512 + sub);
    zr2 = *(const f32x4*)(zx + ((long)(0 * NG + 2) * 16 + wg) * 512 + sub);
    zr3 = *(const f32x4*)(zx + ((long)(0 * NG + 3) * 16 + wg) * 512 + sub);
  }

  __syncthreads();   // one-time full sync (ownw + cs visible)

  for (int t = 0; t < S_; ++t) {
    const unsigned tagbit = (unsigned)((t >> 1) & 1);

    auto phase = [&](auto GC, u64 (&hvC)[4], u64 (&hvN)[4], f32x4& zr) {
      constexpr int g = GC.value;

      // 1. tag-check the pre-blasted words; retry only stale ones
      if (!own) {
        u64* hsrc = hex + (t & 1) * 4096 + g * 1024;
        unsigned need = 0;
        #pragma unroll
        for (int k = 0; k < 4; ++k)
          if (((unsigned)(hvC[k] >> 32) & 1u) != tagbit) need |= 1u << k;
        while (__ballot(need != 0u) != 0ull) {
          u64 tmp[4];
          #pragma unroll
          for (int k = 0; k < 4; ++k)
            if (need & (1u << k))
              tmp[k] = __hip_atomic_load(hsrc + (k << 8) + tid, __ATOMIC_RELAXED,
                                         __HIP_MEMORY_SCOPE_AGENT);
          #pragma unroll
          for (int k = 0; k < 4; ++k)
            if ((need & (1u << k)) && (((unsigned)(tmp[k] >> 32) & 1u) == tagbit)) {
              hvC[k] = tmp[k];
              need &= ~(1u << k);
            }
        }
      }

      // 2. stage h into split hi/lo LDS planes (own slice straight from LDS)
      #pragma unroll
      for (int k = 0; k < 4; ++k) {
        int b  = k * 2 + (tid >> 7);
        int u2 = tid & 127;
        u64 w = own ? ownw[g][b * 8 + (tid & 7)] : hvC[k];
        *(unsigned*)&hhp[g][b * 264 + u2 * 2] = (unsigned)w;
        *(unsigned*)&hlp[g][b * 264 + u2 * 2] = (unsigned)(w >> 32);
      }

      // 3. pre-blast group (g+2)&3: its publish was 2 phases ago (visible);
      //    its consumption is 2 phases ahead (load returned by then).
      if (!own) {
        const int tj = t + (g >= 2 ? 1 : 0);
        u64* bsrc = hex + (tj & 1) * 4096 + ((g + 2) & 3) * 1024;
        #pragma unroll
        for (int k = 0; k < 4; ++k)
          hvN[k] = __hip_atomic_load(bsrc + (k << 8) + tid, __ATOMIC_RELAXED,
                                     __HIP_MEMORY_SCOPE_AGENT);
      }
      bar_lds();   // SYNC1 (lgkm only -- poll/zx loads stay in flight)

      // 4. MFMA: M=8 rows (rows 8-15 duplicate rows 0-7, discarded)
      f32x4 accH = {0.f, 0.f, 0.f, 0.f}, accM = {0.f, 0.f, 0.f, 0.f};
      #pragma unroll
      for (int kc = 0; kc < 8; ++kc) {
        short8 ahh = *(const short8*)&hhp[g][(mm & 7) * 264 + kc * 32 + q * 8];
        short8 ahl = *(const short8*)&hlp[g][(mm & 7) * 264 + kc * 32 + q * 8];
        accH = __builtin_amdgcn_mfma_f32_16x16x32_bf16(ahh, whh[kc], accH, 0, 0, 0);
        accM = __builtin_amdgcn_mfma_f32_16x16x32_bf16(ahh, whl[kc], accM, 0, 0, 0);
        accM = __builtin_amdgcn_mfma_f32_16x16x32_bf16(ahl, whh[kc], accM, 0, 0, 0);
      }
      if (q < 2) {
        #pragma unroll
        for (int r = 0; r < 4; ++r)
          zbuf[(q * 4 + r) * 68 + wv * 16 + mm] = fast_tanh(accH[r] + accM[r] + zr[r]);
        // 5. reload zx for this group's next step (consumed 4 phases later)
        int tn = (t + 1 < S_) ? (t + 1) : t;
        zr = *(const f32x4*)(zx + ((long)(tn * NG + g) * 16 + wg) * 512 +
                             wv * 128 + (lane & 31) * 4);
      }
      bar_lds();   // SYNC2

      // 6. combine: one unit per thread; shfl pairs units for the packed word
      if (tid < 128) {
        float zi = zbuf[cb * 68 +  0 + cu];
        float zf = zbuf[cb * 68 + 16 + cu];
        float zg = zbuf[cb * 68 + 32 + cu];
        float zo = zbuf[cb * 68 + 48 + cu];
        float ig = fast_sig(zi);
        float fg = fast_sig(zf);
        float gg = fast_tanh(zg);
        float og = fast_sig(zo);
        float cn = fg * cs4[g] + ig * gg;
        cs4[g] = cn;
        float hn = fast_tanh(cn) * og;
        float hp = __shfl_xor(hn, 1);
        if ((cu & 1) == 0) {
          *(float2*)(out + ((long)(g * MB + cb) * S_ + t) * H_ + wg * UPW + cu) =
              make_float2(hn, hp);
          const unsigned tagw = (unsigned)(((t + 1) >> 1) & 1);
          u64 word = packw(hn, hp, tagw);
          ownw[g][cb * 8 + (cu >> 1)] = word;
          __hip_atomic_store(hex + ((t + 1) & 1) * 4096 + g * 1024 +
                                 cb * 128 + wg * 8 + (cu >> 1),
                             word, __ATOMIC_RELAXED, __HIP_MEMORY_SCOPE_AGENT);
        }
      }
    };

    phase(std::integral_constant<int, 0>{}, hv0, hv2, zr0);
    phase(std::integral_constant<int, 1>{}, hv1, hv3, zr1);
    phase(std::integral_constant<int, 2>{}, hv2, hv0, zr2);
    phase(std::integral_constant<int, 3>{}, hv3, hv1, zr3);
  }
}

// ===================== legacy fallback (small-workspace) path =====================

__global__ void pack_h0_kernel(const float* __restrict__ h0, u64* __restrict__ hex) {
  int idx = blockIdx.x * 256 + threadIdx.x;       // 0..4095
  float v0 = h0[idx * 2], v1 = h0[idx * 2 + 1];
  hex[idx] = packw(v0, v1, 0u);
}

__global__ __launch_bounds__(NT, 1) void lstm_persist_fb(
    const float* __restrict__ x, const float* __restrict__ c0,
    const float* __restrict__ W, const float* __restrict__ bias,
    float* __restrict__ out, u64* __restrict__ hex) {

  __shared__ unsigned short hh_lds[32 * 264];
  __shared__ unsigned short hl_lds[32 * 264];
  __shared__ float zbuf[32 * 68];
  __shared__ unsigned short xlds[32 * 264];

  const int tid  = threadIdx.x;
  const int wg   = blockIdx.x;
  const int lane = tid & 63;
  const int wv   = tid >> 6;
  const int mt   = wv & 1;
  const int ct0  = (wv >> 1) * 2;
  const int q    = lane >> 4;
  const int mm   = lane & 15;

  short8 whh[2][8], whl[2][8], wx[2][8];
  float  bia[2];
  #pragma unroll
  for (int c = 0; c < 2; ++c) {
    const int col = (ct0 + c) * 256 + wg * UPW + mm;
    #pragma unroll
    for (int kc = 0; kc < 8; ++kc) {
      short8 vhh, vhl, vx;
      #pragma unroll
      for (int j = 0; j < 8; ++j) {
        int k = kc * 32 + q * 8 + j;
        float whv = W[(long)(256 + k) * 1024 + col];
        unsigned short hh = f2bf(whv);
        vhh[j] = (short)hh;
        vhl[j] = (short)f2bf(whv - bf2f(hh));
        vx[j] = (short)f2bf(W[(long)k * 1024 + col]);
      }
      whh[c][kc] = vhh; whl[c][kc] = vhl; wx[c][kc] = vx;
    }
    bia[c] = bias[(ct0 + c) * 256 + wg * UPW + mm];
  }

  const int cb  = tid >> 3;
  const int cu0 = (tid & 7) * 2;
  float cst[2];
  cst[0] = c0[cb * 256 + wg * UPW + cu0];
  cst[1] = c0[cb * 256 + wg * UPW + cu0 + 1];

  u64* const hex0 = hex;
  u64* const hex1 = hex + 4096;

  for (int t = 0; t < S_; ++t) {
    u64* const hsrc8 = (t & 1) ? hex1 : hex0;
    u64* const hdst8 = (t & 1) ? hex0 : hex1;
    const unsigned tagbit = (unsigned)((t >> 1) & 1);

    u64 hv[16];
    #pragma unroll
    for (int k = 0; k < 16; ++k)
      hv[k] = __hip_atomic_load(hsrc8 + (k << 8) + tid, __ATOMIC_RELAXED,
                                __HIP_MEMORY_SCOPE_AGENT);
    unsigned need = 0;
    #pragma unroll
    for (int k = 0; k < 16; ++k)
      if (((unsigned)(hv[k] >> 32) & 1u) != tagbit) need |= 1u << k;
    while (__ballot(need != 0u) != 0ull) {
      u64 tmp[16];
      #pragma unroll
      for (int k = 0; k < 16; ++k)
        if (need & (1u << k))
          tmp[k] = __hip_atomic_load(hsrc8 + (k << 8) + tid, __ATOMIC_RELAXED,
                                     __HIP_MEMORY_SCOPE_AGENT);
      #pragma unroll
      for (int k = 0; k < 16; ++k)
        if ((need & (1u << k)) && (((unsigned)(tmp[k] >> 32) & 1u) == tagbit)) {
          hv[k] = tmp[k];
          need &= ~(1u << k);
        }
    }

    #pragma unroll
    for (int k = 0; k < 16; ++k) {
      int b  = k * 2 + (tid >> 7);
      int du = (tid & 127);
      *(unsigned*)&hh_lds[b * 264 + du * 2] = (unsigned)hv[k];
      *(unsigned*)&hl_lds[b * 264 + du * 2] = (unsigned)(hv[k] >> 32);
    }
    {
      const int xb = tid >> 3, xi0 = (tid & 7) * 32;
      const float* xp = x + ((long)xb * S_ + t) * I_ + xi0;
      #pragma unroll
      for (int k2 = 0; k2 < 4; ++k2) {
        f32x4 a  = *(const f32x4*)(xp + k2 * 8);
        f32x4 b2 = *(const f32x4*)(xp + k2 * 8 + 4);
        unsigned short u8[8];
        #pragma unroll
        for (int j = 0; j < 4; ++j) { u8[j] = f2bf(a[j]); u8[4 + j] = f2bf(b2[j]); }
        *(uint4*)&xlds[xb * 264 + xi0 + k2 * 8] = *(const uint4*)u8;
      }
    }
    __syncthreads();

    f32x4 accH[2], accM[2], accX[2];
    #pragma unroll
    for (int c = 0; c < 2; ++c) {
      accH[c] = (f32x4){0.f, 0.f, 0.f, 0.f};
      accM[c] = (f32x4){0.f, 0.f, 0.f, 0.f};
      accX[c] = (f32x4){0.f, 0.f, 0.f, 0.f};
    }
    const int arow = mm + 16 * mt;
    #pragma unroll
    for (int kc = 0; kc < 8; ++kc) {
      short8 ahh = *(const short8*)&hh_lds[arow * 264 + kc * 32 + q * 8];
      short8 ahl = *(const short8*)&hl_lds[arow * 264 + kc * 32 + q * 8];
      short8 ax  = *(const short8*)&xlds[arow * 264 + kc * 32 + q * 8];
      #pragma unroll
      for (int c = 0; c < 2; ++c) {
        accH[c] = __builtin_amdgcn_mfma_f32_16x16x32_bf16(ahh, whh[c][kc], accH[c], 0, 0, 0);
        accM[c] = __builtin_amdgcn_mfma_f32_16x16x32_bf16(ahh, whl[c][kc], accM[c], 0, 0, 0);
        accM[c] = __builtin_amdgcn_mfma_f32_16x16x32_bf16(ahl, whh[c][kc], accM[c], 0, 0, 0);
        accX[c] = __builtin_amdgcn_mfma_f32_16x16x32_bf16(ax, wx[c][kc], accX[c], 0, 0, 0);
      }
    }
    #pragma unroll
    for (int c = 0; c < 2; ++c) {
      #pragma unroll
      for (int r = 0; r < 4; ++r) {
        float zp = accH[c][r] + accM[c][r] + accX[c][r] + bia[c];
        int brow = q * 4 + r + 16 * mt;
        zbuf[brow * 68 + (ct0 + c) * 16 + mm] = fast_tanh(zp);
      }
    }
    __syncthreads();

    float hn2[2];
    #pragma unroll
    for (int j = 0; j < 2; ++j) {
      int u = cu0 + j;
      float zi = zbuf[cb * 68 +  0 + u];
      float zf = zbuf[cb * 68 + 16 + u];
      float zg = zbuf[cb * 68 + 32 + u];
      float zo = zbuf[cb * 68 + 48 + u];
      float ig = fast_sig(zi);
      float fg = fast_sig(zf);
      float gg = fast_tanh(zg);
      float og = fast_sig(zo);
      float cn = fg * cst[j] + ig * gg;
      cst[j] = cn;
      hn2[j] = fast_tanh(cn) * og;
    }
    *(float2*)(out + ((long)cb * S_ + t) * H_ + wg * UPW + cu0) =
        make_float2(hn2[0], hn2[1]);
    {
      const unsigned tagw = (unsigned)(((t + 1) >> 1) & 1);
      u64 word = packw(hn2[0], hn2[1], tagw);
      __hip_atomic_store(hdst8 + cb * 128 + wg * 8 + (cu0 >> 1), word,
                         __ATOMIC_RELAXED, __HIP_MEMORY_SCOPE_AGENT);
    }
  }
}

extern "C" void kernel_launch(void* const* d_in, const int* in_sizes, int n_in,
                              void* d_out, int out_size, void* d_ws, size_t ws_size,
                              hipStream_t stream) {
  const float* x    = (const float*)d_in[0];
  const float* h0   = (const float*)d_in[1];
  const float* c0   = (const float*)d_in[2];
  const float* W    = (const float*)d_in[3];
  const float* bias = (const float*)d_in[4];
  float* out = (float*)d_out;

  // ws layout: [0, 64K) h exchange, [64K, 64K+256M) zx
  u64*   hex = (u64*)d_ws;
  float* zx  = (float*)((char*)d_ws + 65536);
  const size_t zx_bytes = (size_t)S_ * B_ * 4 * H_ * sizeof(float);  // 256 MiB

  // outputs 1 and 2 of the reference are zeros
  hipMemsetAsync((char*)d_out + (size_t)B_ * S_ * H_ * 4, 0, 2 * B_ * H_ * 4, stream);

  if (ws_size >= 65536 + zx_bytes) {
    // parity-1 half starts all-ones -> tag bit 1, invalid for its first
    // consumers (t=1, expected tag 0)
    hipMemsetAsync((char*)d_ws + 32768, 0xFF, 32768, stream);
    pack_h0_4grp<<<16, 256, 0, stream>>>(h0, hex);
    zx_precompute4<<<(S_ / TC) * 16, NT, 0, stream>>>(x, W, bias, zx);
    lstm_persist4<<<NWG, NT, 0, stream>>>(h0, c0, out, hex, W, zx);
  } else {
    hipMemsetAsync((char*)d_ws + 32768, 0xFF, 32768, stream);
    pack_h0_kernel<<<16, 256, 0, stream>>>(h0, hex);
    lstm_persist_fb<<<NWG, NT, 0, stream>>>(x, c0, W, bias, out, hex);
  }
}

// Round 3
// 8018.229 us; speedup vs baseline: 1.3766x; 1.3766x over previous
//
#include <hip/hip_runtime.h>
#include <hip/hip_bf16.h>

// Problem constants
#define B_   32
#define S_   2048
#define I_   256
#define H_   256
#define NWG  16      // workgroups in the persistent kernel
#define NT   256     // threads per WG
#define TC   16      // timesteps per precompute WG

typedef __attribute__((ext_vector_type(8))) short short8;   // 8 x bf16 MFMA frag
typedef __attribute__((ext_vector_type(4))) float f32x4;
typedef unsigned long long u64;

__device__ __forceinline__ unsigned short f2bf(float f) {
  unsigned u = __builtin_bit_cast(unsigned, f);
  return (unsigned short)((u + 0x7FFFu + ((u >> 16) & 1u)) >> 16);  // RNE
}
__device__ __forceinline__ float bf2f(unsigned short b) {
  unsigned u = ((unsigned)b) << 16;
  return __builtin_bit_cast(float, u);
}
__device__ __forceinline__ float fast_rcp(float x) { return __builtin_amdgcn_rcpf(x); }
// |inputs| are bounded (<~8) in this net: no overflow concerns.
__device__ __forceinline__ float fast_tanh(float x) {
  return 1.f - 2.f * fast_rcp(__expf(2.f * x) + 1.f);
}
__device__ __forceinline__ float fast_sig(float x) {
  return fast_rcp(1.f + __expf(-x));
}
// Pack 2 hidden units into one exchange word: low dword = (hi0|hi1<<16),
// high dword = (lo0|lo1<<16) with tag in lo0's LSB.
__device__ __forceinline__ u64 packw(float v0, float v1, unsigned tagw) {
  unsigned short h0h = f2bf(v0);
  unsigned short h0l = f2bf(v0 - bf2f(h0h));
  unsigned short h1h = f2bf(v1);
  unsigned short h1l = f2bf(v1 - bf2f(h1h));
  unsigned hiw = (unsigned)h0h | ((unsigned)h1h << 16);
  unsigned low = (((unsigned)h0l & 0xFFFEu) | tagw) | ((unsigned)h1l << 16);
  return (u64)hiw | ((u64)low << 32);
}

// ===================== wave-autonomous path =====================
// 64 waves (16 WGs x 4). Wave gw: ug = gw>>1 owns hidden units [ug*8, ug*8+8)
// for ALL 4 gates (combine is wave-local); slot = gw&1 interleaves batch
// groups A = slot and B = slot+2 (8 batches each) so each group's exchange
// round trip hides under the other group's compute. ZERO barriers: all LDS
// is per-wave (lgkmcnt-ordered), skew between waves is absorbed elastically.
//
// Exchange (u64): idx = parity*4096 + bg*1024 + b*128 + up
//   (parity = t&1, bg 0..3, b = batch-in-group 0..7, up = unit pair 0..127).
// Validity: tag bit (lo0 LSB) == (t>>1)&1. Producer of (bg,b,up) is wave
// (ug'=up>>2, slot'=bg&1). 2-buffer overwrite safety: P publishes bg@t+2 only
// after consuming all bg@t+1, whose producers consumed all bg@t first.

__global__ void pack_h0_4grp(const float* __restrict__ h0, u64* __restrict__ hex) {
  int idx = blockIdx.x * 256 + threadIdx.x;   // 0..4095 (parity-0 words)
  int g   = idx >> 10;
  int rem = idx & 1023;
  int b   = rem >> 7;
  int u2  = rem & 127;
  const float* hp = h0 + ((g * 8 + b) * 256 + u2 * 2);
  hex[g * 1024 + rem] = packw(hp[0], hp[1], 0u);   // tag(t=0) = 0
}

// zx = x@Wx + bias, stored transposed-per-tile for the wave kernel:
// element (t, bg, ug8, n, c, rowbg) at
//   ((t*4+bg)*32 + ug8)*256 + n*128 + c*8 + rowbg
// where n = gate>>1, c = (gate&1)*8 + u', rowbg = batch&7.  (256 MiB)
__global__ __launch_bounds__(NT) void zx_precompute_w(
    const float* __restrict__ x, const float* __restrict__ W,
    const float* __restrict__ bias, float* __restrict__ zx) {
  __shared__ unsigned short xlds[32 * 264];

  const int tid  = threadIdx.x;
  const int ug16 = blockIdx.x & 15;
  const int tc   = blockIdx.x >> 4;
  const int lane = tid & 63;
  const int wv   = tid >> 6;     // wave = gate
  const int q    = lane >> 4;
  const int mm   = lane & 15;

  short8 wx[8];
  const int col = wv * 256 + ug16 * 16 + mm;
  const float bia = bias[col];
  #pragma unroll
  for (int kc = 0; kc < 8; ++kc) {
    short8 v;
    #pragma unroll
    for (int j = 0; j < 8; ++j)
      v[j] = (short)f2bf(W[(long)(kc * 32 + q * 8 + j) * 1024 + col]);
    wx[kc] = v;
  }

  // per-thread store base pieces
  const int ug8  = ug16 * 2 + (mm >> 3);
  const long tail = (long)(wv >> 1) * 128 + ((wv & 1) * 8 + (mm & 7)) * 8 + (q & 1) * 4;

  for (int tt = 0; tt < TC; ++tt) {
    const int t = tc * TC + tt;
    const int xb = tid >> 3, xi0 = (tid & 7) * 32;
    const float* xp = x + ((long)xb * S_ + t) * I_ + xi0;
    #pragma unroll
    for (int k2 = 0; k2 < 4; ++k2) {
      f32x4 a  = *(const f32x4*)(xp + k2 * 8);
      f32x4 b2 = *(const f32x4*)(xp + k2 * 8 + 4);
      unsigned short u8[8];
      #pragma unroll
      for (int j = 0; j < 4; ++j) { u8[j] = f2bf(a[j]); u8[4 + j] = f2bf(b2[j]); }
      *(uint4*)&xlds[xb * 264 + xi0 + k2 * 8] = *(const uint4*)u8;
    }
    __syncthreads();
    f32x4 acc0 = {0.f, 0.f, 0.f, 0.f}, acc1 = {0.f, 0.f, 0.f, 0.f};
    #pragma unroll
    for (int kc = 0; kc < 8; ++kc) {
      short8 a0 = *(const short8*)&xlds[(mm)      * 264 + kc * 32 + q * 8];
      short8 a1 = *(const short8*)&xlds[(16 + mm) * 264 + kc * 32 + q * 8];
      acc0 = __builtin_amdgcn_mfma_f32_16x16x32_bf16(a0, wx[kc], acc0, 0, 0, 0);
      acc1 = __builtin_amdgcn_mfma_f32_16x16x32_bf16(a1, wx[kc], acc1, 0, 0, 0);
    }
    f32x4 s0, s1;
    #pragma unroll
    for (int r = 0; r < 4; ++r) { s0[r] = acc0[r] + bia; s1[r] = acc1[r] + bia; }
    // acc0 rows = batches 0..15 -> bg = q>>1, rowbg = (q&1)*4+r
    // acc1 rows = batches 16..31 -> bg = 2+(q>>1)
    *(f32x4*)(zx + (((long)t * 4 +     (q >> 1)) * 32 + ug8) * 256 + tail) = s0;
    *(f32x4*)(zx + (((long)t * 4 + 2 + (q >> 1)) * 32 + ug8) * 256 + tail) = s1;
    __syncthreads();   // protect xlds before next stage
  }
}

__global__ __launch_bounds__(NT, 1) void lstm_wave(
    const float* __restrict__ c0, float* __restrict__ out,
    u64* __restrict__ hex, const float* __restrict__ W,
    const float* __restrict__ zx) {

  // all LDS strictly per-wave -> no __syncthreads in this kernel at all
  __shared__ unsigned short hhp[4][8 * 264];
  __shared__ unsigned short hlp[4][8 * 264];
  __shared__ float zbp[4][8 * 36];

  const int tid  = threadIdx.x;
  const int wv   = tid >> 6;
  const int lane = tid & 63;
  const int gw   = blockIdx.x * 4 + wv;   // 0..63
  const int ug   = gw >> 1;               // 0..31: units [ug*8, ug*8+8)
  const int slot = gw & 1;
  const int bgA  = slot, bgB = slot + 2;
  const int q    = lane >> 4;
  const int mm   = lane & 15;

  unsigned short* const hh = hhp[wv];
  unsigned short* const hl = hlp[wv];
  float* const zb = zbp[wv];

  // ---- one-time: Wh fragments (hi/lo bf16) for this wave's 32 columns
  // tile n covers gates 2n,2n+1: col(n,mm) = (n*2 + (mm>>3))*256 + ug*8 + (mm&7)
  short8 whh[2][8], whl[2][8];
  #pragma unroll
  for (int n = 0; n < 2; ++n) {
    const int col = (n * 2 + (mm >> 3)) * 256 + ug * 8 + (mm & 7);
    #pragma unroll
    for (int kc = 0; kc < 8; ++kc) {
      short8 vh, vl;
      #pragma unroll
      for (int j = 0; j < 8; ++j) {
        int k = kc * 32 + q * 8 + j;
        float w = W[(long)(256 + k) * 1024 + col];
        unsigned short hi = f2bf(w);
        vh[j] = (short)hi;
        vl[j] = (short)f2bf(w - bf2f(hi));
      }
      whh[n][kc] = vh; whl[n][kc] = vl;
    }
  }

  // combine: lane owns (batch-in-group cbb, unit cuu) for both groups
  const int cbb = lane >> 3, cuu = lane & 7;
  float csA = c0[(bgA * 8 + cbb) * 256 + ug * 8 + cuu];
  float csB = c0[(bgB * 8 + cbb) * 256 + ug * 8 + cuu];

  // pre-blast A(0) words (parity 0, seeded by pack_h0_4grp; stream-ordered)
  u64 hvA[16], hvB[16];
  #pragma unroll
  for (int k = 0; k < 16; ++k)
    hvA[k] = __hip_atomic_load(hex + bgA * 1024 + (k << 6) + lane,
                               __ATOMIC_RELAXED, __HIP_MEMORY_SCOPE_AGENT);

  // zx pipeline regs (single-buffered; reload right after consumption)
  f32x4 zxA[2], zxB[2];
  if (q < 2) {
    const float* zpA = zx + ((long)(0 * 4 + bgA) * 32 + ug) * 256 + mm * 8 + q * 4;
    const float* zpB = zx + ((long)(0 * 4 + bgB) * 32 + ug) * 256 + mm * 8 + q * 4;
    zxA[0] = *(const f32x4*)zpA; zxA[1] = *(const f32x4*)(zpA + 128);
    zxB[0] = *(const f32x4*)zpB; zxB[1] = *(const f32x4*)(zpB + 128);
  }

  auto phase = [&](int bg, int t, u64 (&hvC)[16], u64 (&hvN)[16],
                   int nbg, int nparity, f32x4 (&zxc)[2], float& cs) {
    const unsigned tagbit = (unsigned)((t >> 1) & 1);

    // 1. tag-check pre-blasted words; retry only stale ones (wave-local spin)
    unsigned need = 0;
    #pragma unroll
    for (int k = 0; k < 16; ++k)
      if (((unsigned)(hvC[k] >> 32) & 1u) != tagbit) need |= 1u << k;
    if (__ballot(need != 0u) != 0ull) {
      u64* hsrc = hex + (t & 1) * 4096 + bg * 1024;
      do {
        u64 tmp[16];
        #pragma unroll
        for (int k = 0; k < 16; ++k)
          if (need & (1u << k))
            tmp[k] = __hip_atomic_load(hsrc + (k << 6) + lane, __ATOMIC_RELAXED,
                                       __HIP_MEMORY_SCOPE_AGENT);
        #pragma unroll
        for (int k = 0; k < 16; ++k)
          if ((need & (1u << k)) && (((unsigned)(tmp[k] >> 32) & 1u) == tagbit)) {
            hvC[k] = tmp[k];
            need &= ~(1u << k);
          }
      } while (__ballot(need != 0u) != 0ull);
    }

    // 2. stage h into this wave's hi/lo LDS planes (lane-stride 4B: conflict-free)
    #pragma unroll
    for (int k = 0; k < 16; ++k) {
      int b  = k >> 1;
      int up = ((k & 1) << 6) + lane;
      *(unsigned*)&hh[b * 264 + up * 2] = (unsigned)hvC[k];
      *(unsigned*)&hl[b * 264 + up * 2] = (unsigned)(hvC[k] >> 32);
    }

    // 3. blast the NEXT phase's words (latency hides under this phase's MFMA
    //    + combine; tag-retry there covers late producers). Never waited here.
    {
      u64* bsrc = hex + nparity * 4096 + nbg * 1024;
      #pragma unroll
      for (int k = 0; k < 16; ++k)
        hvN[k] = __hip_atomic_load(bsrc + (k << 6) + lane, __ATOMIC_RELAXED,
                                   __HIP_MEMORY_SCOPE_AGENT);
    }

    // wave-local LDS ordering only (no barrier, vmcnt never drained)
    asm volatile("s_waitcnt lgkmcnt(0)" ::: "memory");
    __builtin_amdgcn_sched_barrier(0);

    // 4. MFMA: M=8 batches (rows 8-15 duplicate, discarded), N=32, K=256
    f32x4 aH[2], aM[2];
    aH[0] = aH[1] = aM[0] = aM[1] = (f32x4){0.f, 0.f, 0.f, 0.f};
    #pragma unroll
    for (int kc = 0; kc < 8; ++kc) {
      short8 ahh = *(const short8*)&hh[(mm & 7) * 264 + kc * 32 + q * 8];
      short8 ahl = *(const short8*)&hl[(mm & 7) * 264 + kc * 32 + q * 8];
      #pragma unroll
      for (int n = 0; n < 2; ++n) {
        aH[n] = __builtin_amdgcn_mfma_f32_16x16x32_bf16(ahh, whh[n][kc], aH[n], 0, 0, 0);
        aM[n] = __builtin_amdgcn_mfma_f32_16x16x32_bf16(ahh, whl[n][kc], aM[n], 0, 0, 0);
        aM[n] = __builtin_amdgcn_mfma_f32_16x16x32_bf16(ahl, whh[n][kc], aM[n], 0, 0, 0);
      }
    }

    // 5. z = tanh(zx + h@Wh) -> zbuf [batch][gate*8+u']; then zx reload (t+1)
    if (q < 2) {
      #pragma unroll
      for (int n = 0; n < 2; ++n)
        #pragma unroll
        for (int r = 0; r < 4; ++r)
          zb[(q * 4 + r) * 36 + n * 16 + mm] =
              fast_tanh(aH[n][r] + aM[n][r] + zxc[n][r]);
      int tn = (t + 1 < S_) ? (t + 1) : t;
      const float* zp = zx + ((long)(tn * 4 + bg) * 32 + ug) * 256 + mm * 8 + q * 4;
      zxc[0] = *(const f32x4*)zp;
      zxc[1] = *(const f32x4*)(zp + 128);
    }

    asm volatile("s_waitcnt lgkmcnt(0)" ::: "memory");
    __builtin_amdgcn_sched_barrier(0);

    // 6. combine (wave-local: this wave owns all 4 gates of its units)
    float zi = zb[cbb * 36 +  0 + cuu];
    float zf = zb[cbb * 36 +  8 + cuu];
    float zg = zb[cbb * 36 + 16 + cuu];
    float zo = zb[cbb * 36 + 24 + cuu];
    float ig = fast_sig(zi);
    float fg = fast_sig(zf);
    float gg = fast_tanh(zg);
    float og = fast_sig(zo);
    float cn = fg * cs + ig * gg;
    cs = cn;
    float hn = fast_tanh(cn) * og;
    float hq = __shfl_xor(hn, 1);
    if ((lane & 1) == 0) {
      *(float2*)(out + ((long)(bg * 8 + cbb) * S_ + t) * H_ + ug * 8 + cuu) =
          make_float2(hn, hq);
      u64 word = packw(hn, hq, (unsigned)(((t + 1) >> 1) & 1));
      __hip_atomic_store(hex + ((t + 1) & 1) * 4096 + bg * 1024 + cbb * 128 +
                             ug * 4 + (cuu >> 1),
                         word, __ATOMIC_RELAXED, __HIP_MEMORY_SCOPE_AGENT);
    }
  };

  for (int t = 0; t < S_; ++t) {
    // at A(t): blast B(t)   (published at end of producers' B(t-1))
    phase(bgA, t, hvA, hvB, bgB, (t & 1), zxA, csA);
    // at B(t): blast A(t+1) (published at end of producers' A(t))
    phase(bgB, t, hvB, hvA, bgA, ((t + 1) & 1), zxB, csB);
  }
}

// ===================== legacy fallback (small-workspace) path =====================

__global__ void pack_h0_kernel(const float* __restrict__ h0, u64* __restrict__ hex) {
  int idx = blockIdx.x * 256 + threadIdx.x;       // 0..4095
  float v0 = h0[idx * 2], v1 = h0[idx * 2 + 1];
  hex[idx] = packw(v0, v1, 0u);
}

__global__ __launch_bounds__(NT, 1) void lstm_persist_fb(
    const float* __restrict__ x, const float* __restrict__ c0,
    const float* __restrict__ W, const float* __restrict__ bias,
    float* __restrict__ out, u64* __restrict__ hex) {

  __shared__ unsigned short hh_lds[32 * 264];
  __shared__ unsigned short hl_lds[32 * 264];
  __shared__ float zbuf[32 * 68];
  __shared__ unsigned short xlds[32 * 264];

  const int tid  = threadIdx.x;
  const int wg   = blockIdx.x;
  const int lane = tid & 63;
  const int wv   = tid >> 6;
  const int mt   = wv & 1;
  const int ct0  = (wv >> 1) * 2;
  const int q    = lane >> 4;
  const int mm   = lane & 15;

  short8 whh[2][8], whl[2][8], wx[2][8];
  float  bia[2];
  #pragma unroll
  for (int c = 0; c < 2; ++c) {
    const int col = (ct0 + c) * 256 + wg * 16 + mm;
    #pragma unroll
    for (int kc = 0; kc < 8; ++kc) {
      short8 vhh, vhl, vx;
      #pragma unroll
      for (int j = 0; j < 8; ++j) {
        int k = kc * 32 + q * 8 + j;
        float whv = W[(long)(256 + k) * 1024 + col];
        unsigned short hh = f2bf(whv);
        vhh[j] = (short)hh;
        vhl[j] = (short)f2bf(whv - bf2f(hh));
        vx[j] = (short)f2bf(W[(long)k * 1024 + col]);
      }
      whh[c][kc] = vhh; whl[c][kc] = vhl; wx[c][kc] = vx;
    }
    bia[c] = bias[(ct0 + c) * 256 + wg * 16 + mm];
  }

  const int cb  = tid >> 3;
  const int cu0 = (tid & 7) * 2;
  float cst[2];
  cst[0] = c0[cb * 256 + wg * 16 + cu0];
  cst[1] = c0[cb * 256 + wg * 16 + cu0 + 1];

  u64* const hex0 = hex;
  u64* const hex1 = hex + 4096;

  for (int t = 0; t < S_; ++t) {
    u64* const hsrc8 = (t & 1) ? hex1 : hex0;
    u64* const hdst8 = (t & 1) ? hex0 : hex1;
    const unsigned tagbit = (unsigned)((t >> 1) & 1);

    u64 hv[16];
    #pragma unroll
    for (int k = 0; k < 16; ++k)
      hv[k] = __hip_atomic_load(hsrc8 + (k << 8) + tid, __ATOMIC_RELAXED,
                                __HIP_MEMORY_SCOPE_AGENT);
    unsigned need = 0;
    #pragma unroll
    for (int k = 0; k < 16; ++k)
      if (((unsigned)(hv[k] >> 32) & 1u) != tagbit) need |= 1u << k;
    while (__ballot(need != 0u) != 0ull) {
      u64 tmp[16];
      #pragma unroll
      for (int k = 0; k < 16; ++k)
        if (need & (1u << k))
          tmp[k] = __hip_atomic_load(hsrc8 + (k << 8) + tid, __ATOMIC_RELAXED,
                                     __HIP_MEMORY_SCOPE_AGENT);
      #pragma unroll
      for (int k = 0; k < 16; ++k)
        if ((need & (1u << k)) && (((unsigned)(tmp[k] >> 32) & 1u) == tagbit)) {
          hv[k] = tmp[k];
          need &= ~(1u << k);
        }
    }

    #pragma unroll
    for (int k = 0; k < 16; ++k) {
      int b  = k * 2 + (tid >> 7);
      int du = (tid & 127);
      *(unsigned*)&hh_lds[b * 264 + du * 2] = (unsigned)hv[k];
      *(unsigned*)&hl_lds[b * 264 + du * 2] = (unsigned)(hv[k] >> 32);
    }
    {
      const int xb = tid >> 3, xi0 = (tid & 7) * 32;
      const float* xp = x + ((long)xb * S_ + t) * I_ + xi0;
      #pragma unroll
      for (int k2 = 0; k2 < 4; ++k2) {
        f32x4 a  = *(const f32x4*)(xp + k2 * 8);
        f32x4 b2 = *(const f32x4*)(xp + k2 * 8 + 4);
        unsigned short u8[8];
        #pragma unroll
        for (int j = 0; j < 4; ++j) { u8[j] = f2bf(a[j]); u8[4 + j] = f2bf(b2[j]); }
        *(uint4*)&xlds[xb * 264 + xi0 + k2 * 8] = *(const uint4*)u8;
      }
    }
    __syncthreads();

    f32x4 accH[2], accM[2], accX[2];
    #pragma unroll
    for (int c = 0; c < 2; ++c) {
      accH[c] = (f32x4){0.f, 0.f, 0.f, 0.f};
      accM[c] = (f32x4){0.f, 0.f, 0.f, 0.f};
      accX[c] = (f32x4){0.f, 0.f, 0.f, 0.f};
    }
    const int arow = mm + 16 * mt;
    #pragma unroll
    for (int kc = 0; kc < 8; ++kc) {
      short8 ahh = *(const short8*)&hh_lds[arow * 264 + kc * 32 + q * 8];
      short8 ahl = *(const short8*)&hl_lds[arow * 264 + kc * 32 + q * 8];
      short8 ax  = *(const short8*)&xlds[arow * 264 + kc * 32 + q * 8];
      #pragma unroll
      for (int c = 0; c < 2; ++c) {
        accH[c] = __builtin_amdgcn_mfma_f32_16x16x32_bf16(ahh, whh[c][kc], accH[c], 0, 0, 0);
        accM[c] = __builtin_amdgcn_mfma_f32_16x16x32_bf16(ahh, whl[c][kc], accM[c], 0, 0, 0);
        accM[c] = __builtin_amdgcn_mfma_f32_16x16x32_bf16(ahl, whh[c][kc], accM[c], 0, 0, 0);
        accX[c] = __builtin_amdgcn_mfma_f32_16x16x32_bf16(ax, wx[c][kc], accX[c], 0, 0, 0);
      }
    }
    #pragma unroll
    for (int c = 0; c < 2; ++c) {
      #pragma unroll
      for (int r = 0; r < 4; ++r) {
        float zp = accH[c][r] + accM[c][r] + accX[c][r] + bia[c];
        int brow = q * 4 + r + 16 * mt;
        zbuf[brow * 68 + (ct0 + c) * 16 + mm] = fast_tanh(zp);
      }
    }
    __syncthreads();

    float hn2[2];
    #pragma unroll
    for (int j = 0; j < 2; ++j) {
      int u = cu0 + j;
      float zi = zbuf[cb * 68 +  0 + u];
      float zf = zbuf[cb * 68 + 16 + u];
      float zg = zbuf[cb * 68 + 32 + u];
      float zo = zbuf[cb * 68 + 48 + u];
      float ig = fast_sig(zi);
      float fg = fast_sig(zf);
      float gg = fast_tanh(zg);
      float og = fast_sig(zo);
      float cn = fg * cst[j] + ig * gg;
      cst[j] = cn;
      hn2[j] = fast_tanh(cn) * og;
    }
    *(float2*)(out + ((long)cb * S_ + t) * H_ + wg * 16 + cu0) =
        make_float2(hn2[0], hn2[1]);
    {
      const unsigned tagw = (unsigned)(((t + 1) >> 1) & 1);
      u64 word = packw(hn2[0], hn2[1], tagw);
      __hip_atomic_store(hdst8 + cb * 128 + wg * 8 + (cu0 >> 1), word,
                         __ATOMIC_RELAXED, __HIP_MEMORY_SCOPE_AGENT);
    }
  }
}

extern "C" void kernel_launch(void* const* d_in, const int* in_sizes, int n_in,
                              void* d_out, int out_size, void* d_ws, size_t ws_size,
                              hipStream_t stream) {
  const float* x    = (const float*)d_in[0];
  const float* h0   = (const float*)d_in[1];
  const float* c0   = (const float*)d_in[2];
  const float* W    = (const float*)d_in[3];
  const float* bias = (const float*)d_in[4];
  float* out = (float*)d_out;

  // ws layout: [0, 64K) h exchange, [64K, 64K+256M) zx
  u64*   hex = (u64*)d_ws;
  float* zx  = (float*)((char*)d_ws + 65536);
  const size_t zx_bytes = (size_t)S_ * B_ * 4 * H_ * sizeof(float);  // 256 MiB

  // outputs 1 and 2 of the reference are zeros
  hipMemsetAsync((char*)d_out + (size_t)B_ * S_ * H_ * 4, 0, 2 * B_ * H_ * 4, stream);

  if (ws_size >= 65536 + zx_bytes) {
    // parity-1 half starts all-ones -> tag bit 1, invalid for its first
    // consumers (t=1, expected tag 0)
    hipMemsetAsync((char*)d_ws + 32768, 0xFF, 32768, stream);
    pack_h0_4grp<<<16, 256, 0, stream>>>(h0, hex);
    zx_precompute_w<<<(S_ / TC) * 16, NT, 0, stream>>>(x, W, bias, zx);
    lstm_wave<<<NWG, NT, 0, stream>>>(c0, out, hex, W, zx);
  } else {
    hipMemsetAsync((char*)d_ws + 32768, 0xFF, 32768, stream);
    pack_h0_kernel<<<16, 256, 0, stream>>>(h0, hex);
    lstm_persist_fb<<<NWG, NT, 0, stream>>>(x, c0, W, bias, out, hex);
  }
}